// Round 6
// baseline (64.820 us; speedup 1.0000x reference)
//
#include <hip/hip_runtime.h>
#include <stdint.h>

// B=8 S=4096 D=768 E=8 R=8; NTOK=32768
// GEMM1: H[NTOK,80] = x @ W1[768,80]   (W1 = [Wd(64) | Wg(8) | pad(8)])
// middle: softmax gate, h2 = (H+bd)@Wm+bm, g2 = [gate*h2 | gate | zeros]  (96 wide, bf16)
// GEMM2: out[NTOK,768] = g2 @ W2[96,768] (W2 rows = [Wu(64) | bu(8) | zeros(24)])
// Split: k1 (x->g2, grid 2048), k2 (g2->out, swapped-operand MFMA, x4 stores, grid 2048).

typedef short bf16x8 __attribute__((ext_vector_type(8)));
typedef float f32x4 __attribute__((ext_vector_type(4)));

static __device__ __forceinline__ unsigned short f2bf(float f) {
  union { float f; uint32_t u; } v; v.f = f;
  return (unsigned short)((v.u + 0x7fffu + ((v.u >> 16) & 1u)) >> 16);
}

// w1f frags [K0(24)][f(5)][lane(64)][i(8)]: W1[K0*32+(lane>>4)*8+i][f*16+(lane&15)]
// w2f frags [T(48)][K0(3)][lane(64)][i(8)]: W2[K0*32+(lane>>4)*8+i][T*16+(lane&15)]
__global__ void prep_weights(const float* __restrict__ Wd, const float* __restrict__ Wg,
                             const float* __restrict__ Wu, const float* __restrict__ bu,
                             unsigned short* __restrict__ w1f, unsigned short* __restrict__ w2f) {
  int tid = blockIdx.x * 256 + threadIdx.x;
  const int N1 = 24 * 5 * 64 * 8;   // 61440
  if (tid < N1) {
    int i    = tid & 7;
    int lane = (tid >> 3) & 63;
    int fk   = tid >> 9;
    int f = fk % 5, K0 = fk / 5;
    int k = K0 * 32 + (lane >> 4) * 8 + i;
    int j = f * 16 + (lane & 15);
    float val = 0.f;
    if (j < 64)      val = Wd[(size_t)(j >> 3) * 6144 + (size_t)k * 8 + (j & 7)];
    else if (j < 72) val = Wg[(size_t)k * 8 + (j - 64)];
    w1f[tid] = f2bf(val);
  } else {
    int t2 = tid - N1;
    if (t2 >= 48 * 3 * 64 * 8) return;
    int i    = t2 & 7;
    int lane = (t2 >> 3) & 63;
    int tk   = t2 >> 9;
    int K0 = tk % 3, T = tk / 3;
    int k = K0 * 32 + (lane >> 4) * 8 + i;
    int n = T * 16 + (lane & 15);
    float val = 0.f;
    if (k < 64)      val = Wu[(size_t)(k >> 3) * 6144 + (size_t)(k & 7) * 768 + n];
    else if (k < 72) val = bu[(size_t)(k - 64) * 768 + n];
    w2f[t2] = f2bf(val);
  }
}

// ---------------- k1: x -> g2 (down + gate + mid), 16 tok/block, 4-way K-split ----------------
__global__ __launch_bounds__(256) void k1_g2(
    const float* __restrict__ x,
    const float* __restrict__ bd, const float* __restrict__ Wm,
    const float* __restrict__ bm, const float* __restrict__ bg,
    const unsigned short* __restrict__ w1f, unsigned int* __restrict__ g2) {
  __shared__ float Hs[4][16][81];       // 20736 B

  const int tidx = threadIdx.x;
  const int lane = tidx & 63;
  const int wave = tidx >> 6;       // K quarter
  const int arow = lane & 15;
  const int kgrp = lane >> 4;
  const int tok0 = blockIdx.x * 16;

  {
    const float* xrow = x + (size_t)(tok0 + arow) * 768 + wave * 192 + kgrp * 8;
    f32x4 acc0 = {0,0,0,0}, acc1 = {0,0,0,0}, acc2 = {0,0,0,0}, acc3 = {0,0,0,0}, acc4 = {0,0,0,0};
    const bf16x8* w1v = (const bf16x8*)w1f + (size_t)(wave * 6) * 320 + lane;

    float4 xa[4][2];
    #pragma unroll
    for (int i = 0; i < 4; i++) {
      xa[i][0] = *(const float4*)(xrow + i * 32);
      xa[i][1] = *(const float4*)(xrow + i * 32 + 4);
    }
    #pragma unroll
    for (int i = 0; i < 6; i++) {
      float4 a0 = xa[i & 3][0];
      float4 a1 = xa[i & 3][1];
      if (i + 4 < 6) {
        xa[i & 3][0] = *(const float4*)(xrow + (i + 4) * 32);
        xa[i & 3][1] = *(const float4*)(xrow + (i + 4) * 32 + 4);
      }
      bf16x8 af;
      af[0] = (short)f2bf(a0.x); af[1] = (short)f2bf(a0.y);
      af[2] = (short)f2bf(a0.z); af[3] = (short)f2bf(a0.w);
      af[4] = (short)f2bf(a1.x); af[5] = (short)f2bf(a1.y);
      af[6] = (short)f2bf(a1.z); af[7] = (short)f2bf(a1.w);
      const bf16x8* bb = w1v + i * 320;
      acc0 = __builtin_amdgcn_mfma_f32_16x16x32_bf16(af, bb[0],   acc0, 0, 0, 0);
      acc1 = __builtin_amdgcn_mfma_f32_16x16x32_bf16(af, bb[64],  acc1, 0, 0, 0);
      acc2 = __builtin_amdgcn_mfma_f32_16x16x32_bf16(af, bb[128], acc2, 0, 0, 0);
      acc3 = __builtin_amdgcn_mfma_f32_16x16x32_bf16(af, bb[192], acc3, 0, 0, 0);
      acc4 = __builtin_amdgcn_mfma_f32_16x16x32_bf16(af, bb[256], acc4, 0, 0, 0);
    }
    int hr = kgrp * 4;
    #pragma unroll
    for (int r = 0; r < 4; r++) {
      Hs[wave][hr + r][arow]      = acc0[r];
      Hs[wave][hr + r][16 + arow] = acc1[r];
      Hs[wave][hr + r][32 + arow] = acc2[r];
      Hs[wave][hr + r][48 + arow] = acc3[r];
      Hs[wave][hr + r][64 + arow] = acc4[r];
    }
  }
  __syncthreads();

  if (tidx < 64) {
    int t = tidx >> 2;   // token 0..15
    int c = tidx & 3;
    unsigned int* g2u = g2 + (size_t)(tok0 + t) * 48;
    float lg[8];
    float m = -1e30f;
    #pragma unroll
    for (int e = 0; e < 8; e++) {
      lg[e] = Hs[0][t][64 + e] + Hs[1][t][64 + e] + Hs[2][t][64 + e] + Hs[3][t][64 + e] + bg[e];
      m = fmaxf(m, lg[e]);
    }
    float den = 0.f;
    #pragma unroll
    for (int e = 0; e < 8; e++) { lg[e] = __expf(lg[e] - m); den += lg[e]; }
    float inv = 1.f / den;
    #pragma unroll
    for (int ee = 0; ee < 2; ee++) {
      int e = c * 2 + ee;
      float gate = lg[e] * inv;
      float h[8];
      #pragma unroll
      for (int r = 0; r < 8; r++)
        h[r] = Hs[0][t][e * 8 + r] + Hs[1][t][e * 8 + r] + Hs[2][t][e * 8 + r] +
               Hs[3][t][e * 8 + r] + bd[e * 8 + r];
      #pragma unroll
      for (int q = 0; q < 8; q += 2) {
        float h2a = bm[e * 8 + q], h2b = bm[e * 8 + q + 1];
        #pragma unroll
        for (int r = 0; r < 8; r++) {
          h2a += h[r] * Wm[e * 64 + r * 8 + q];
          h2b += h[r] * Wm[e * 64 + r * 8 + q + 1];
        }
        g2u[e * 4 + (q >> 1)] =
            (unsigned)f2bf(gate * h2a) | ((unsigned)f2bf(gate * h2b) << 16);
      }
    }
    g2u[32 + c] = (unsigned)f2bf(lg[c * 2] * inv) | ((unsigned)f2bf(lg[c * 2 + 1] * inv) << 16);
    g2u[36 + c * 3 + 0] = 0;
    g2u[36 + c * 3 + 1] = 0;
    g2u[36 + c * 3 + 2] = 0;
  }
}

// ---------------- k2: out = g2 @ W2, swapped operands -> f32x4 stores ----------------
// D = mfma(A=W2frag, B=g2frag): col(lane&15)=token, row=(lane>>4)*4+reg = n-in-tile.
// Each lane stores 4 consecutive floats of one out row per T-tile.
__global__ __launch_bounds__(256) void k2_out(
    const unsigned short* __restrict__ g2bf, const unsigned short* __restrict__ w2f,
    float* __restrict__ out) {
  const int tidx = threadIdx.x;
  const int lane = tidx & 63;
  const int wave = tidx >> 6;       // T quarter (12 tiles)
  const int arow = lane & 15;       // token within block / out row
  const int kgrp = lane >> 4;
  const int tok0 = blockIdx.x * 16;

  const unsigned short* grow = g2bf + (size_t)(tok0 + arow) * 96 + kgrp * 8;
  bf16x8 a2_0 = *(const bf16x8*)(grow);
  bf16x8 a2_1 = *(const bf16x8*)(grow + 32);
  bf16x8 a2_2 = *(const bf16x8*)(grow + 64);

  const bf16x8* w2v = (const bf16x8*)w2f + (size_t)(wave * 12) * 192 + lane;
  float* orow = out + (size_t)(tok0 + arow) * 768 + wave * 192 + kgrp * 4;

  bf16x8 pb[4][3];
  #pragma unroll
  for (int d = 0; d < 4; d++) {
    pb[d][0] = w2v[d * 192];
    pb[d][1] = w2v[d * 192 + 64];
    pb[d][2] = w2v[d * 192 + 128];
  }
  #pragma unroll
  for (int j = 0; j < 12; j++) {
    bf16x8 b0 = pb[j & 3][0], b1 = pb[j & 3][1], b2 = pb[j & 3][2];
    if (j + 4 < 12) {
      pb[j & 3][0] = w2v[(j + 4) * 192];
      pb[j & 3][1] = w2v[(j + 4) * 192 + 64];
      pb[j & 3][2] = w2v[(j + 4) * 192 + 128];
    }
    f32x4 c2 = {0,0,0,0};
    c2 = __builtin_amdgcn_mfma_f32_16x16x32_bf16(b0, a2_0, c2, 0, 0, 0);
    c2 = __builtin_amdgcn_mfma_f32_16x16x32_bf16(b1, a2_1, c2, 0, 0, 0);
    c2 = __builtin_amdgcn_mfma_f32_16x16x32_bf16(b2, a2_2, c2, 0, 0, 0);
    *(f32x4*)(orow + j * 16) = c2;
  }
}

extern "C" void kernel_launch(void* const* d_in, const int* in_sizes, int n_in,
                              void* d_out, int out_size, void* d_ws, size_t ws_size,
                              hipStream_t stream) {
  const float* x  = (const float*)d_in[0];
  const float* Wd = (const float*)d_in[1];
  const float* bd = (const float*)d_in[2];
  const float* Wm = (const float*)d_in[3];
  const float* bm = (const float*)d_in[4];
  const float* Wu = (const float*)d_in[5];
  const float* bu = (const float*)d_in[6];
  const float* Wg = (const float*)d_in[7];
  const float* bg = (const float*)d_in[8];
  unsigned short* w1f = (unsigned short*)d_ws;                  // 61440 bf16
  unsigned short* w2f = w1f + 61440;                            // 73728 bf16
  unsigned int*   g2  = (unsigned int*)((char*)d_ws + 270336);  // 32768*48 u32 = 6 MB

  prep_weights<<<528, 256, 0, stream>>>(Wd, Wg, Wu, bu, w1f, w2f);
  k1_g2<<<2048, 256, 0, stream>>>(x, bd, Wm, bm, bg, w1f, g2);
  k2_out<<<2048, 256, 0, stream>>>((const unsigned short*)g2, w2f, (float*)d_out);
}

// Round 7
// 61.659 us; speedup vs baseline: 1.0513x; 1.0513x over previous
//
#include <hip/hip_runtime.h>
#include <stdint.h>

// B=8 S=4096 D=768 E=8 R=8; NTOK=32768
// GEMM1: H[NTOK,80] = x @ W1[768,80]   (W1 = [Wd(64) | Wg(8) | pad(8)])
// middle: softmax gate, h2 = (H+bd)@Wm+bm, g2 = [gate*h2 | gate | zeros]  (96 wide, bf16)
// GEMM2: out[NTOK,768] = g2 @ W2[96,768] (W2 rows = [Wu(64) | bu(8) | zeros(24)])
// Split: k1 (x->g2, 32tok/block grid 1024), k2 (g2->out, 32tok/block grid 1024,
//        swapped-operand MFMA so each lane stores f32x4; W2 frags reused across 2 token groups).

typedef short bf16x8 __attribute__((ext_vector_type(8)));
typedef float f32x4 __attribute__((ext_vector_type(4)));

static __device__ __forceinline__ unsigned short f2bf(float f) {
  union { float f; uint32_t u; } v; v.f = f;
  return (unsigned short)((v.u + 0x7fffu + ((v.u >> 16) & 1u)) >> 16);
}

// w1f frags [K0(24)][f(5)][lane(64)][i(8)]: W1[K0*32+(lane>>4)*8+i][f*16+(lane&15)]
// w2f frags [T(48)][K0(3)][lane(64)][i(8)]: W2[K0*32+(lane>>4)*8+i][T*16+(lane&15)]
__global__ void prep_weights(const float* __restrict__ Wd, const float* __restrict__ Wg,
                             const float* __restrict__ Wu, const float* __restrict__ bu,
                             unsigned short* __restrict__ w1f, unsigned short* __restrict__ w2f) {
  int tid = blockIdx.x * 256 + threadIdx.x;
  const int N1 = 24 * 5 * 64 * 8;   // 61440
  if (tid < N1) {
    int i    = tid & 7;
    int lane = (tid >> 3) & 63;
    int fk   = tid >> 9;
    int f = fk % 5, K0 = fk / 5;
    int k = K0 * 32 + (lane >> 4) * 8 + i;
    int j = f * 16 + (lane & 15);
    float val = 0.f;
    if (j < 64)      val = Wd[(size_t)(j >> 3) * 6144 + (size_t)k * 8 + (j & 7)];
    else if (j < 72) val = Wg[(size_t)k * 8 + (j - 64)];
    w1f[tid] = f2bf(val);
  } else {
    int t2 = tid - N1;
    if (t2 >= 48 * 3 * 64 * 8) return;
    int i    = t2 & 7;
    int lane = (t2 >> 3) & 63;
    int tk   = t2 >> 9;
    int K0 = tk % 3, T = tk / 3;
    int k = K0 * 32 + (lane >> 4) * 8 + i;
    int n = T * 16 + (lane & 15);
    float val = 0.f;
    if (k < 64)      val = Wu[(size_t)(k >> 3) * 6144 + (size_t)(k & 7) * 768 + n];
    else if (k < 72) val = bu[(size_t)(k - 64) * 768 + n];
    w2f[t2] = f2bf(val);
  }
}

// ---------------- k1: x -> g2 (down + gate + mid), 32 tok/block, 2-way K-split ----------------
__global__ __launch_bounds__(256) void k1_g2(
    const float* __restrict__ x,
    const float* __restrict__ bd, const float* __restrict__ Wm,
    const float* __restrict__ bm, const float* __restrict__ bg,
    const unsigned short* __restrict__ w1f, unsigned int* __restrict__ g2) {
  __shared__ float Hs[2][32][84];       // 21504 B; stride 84 -> worst bank overlap 2-way (free)

  const int tidx = threadIdx.x;
  const int lane = tidx & 63;
  const int wave = tidx >> 6;
  const int tg   = wave >> 1;       // token group (16 tokens)
  const int kh   = wave & 1;        // K half
  const int arow = lane & 15;
  const int kgrp = lane >> 4;
  const int tok0 = blockIdx.x * 32;

  {
    const float* xrow = x + (size_t)(tok0 + tg * 16 + arow) * 768 + kh * 384 + kgrp * 8;
    f32x4 acc0 = {0,0,0,0}, acc1 = {0,0,0,0}, acc2 = {0,0,0,0}, acc3 = {0,0,0,0}, acc4 = {0,0,0,0};
    const bf16x8* w1v = (const bf16x8*)w1f + (size_t)(kh * 12) * 320 + lane;

    float4 xa[4][2];
    #pragma unroll
    for (int i = 0; i < 4; i++) {
      xa[i][0] = *(const float4*)(xrow + i * 32);
      xa[i][1] = *(const float4*)(xrow + i * 32 + 4);
    }
    #pragma unroll
    for (int i = 0; i < 12; i++) {
      float4 a0 = xa[i & 3][0];
      float4 a1 = xa[i & 3][1];
      if (i + 4 < 12) {
        xa[i & 3][0] = *(const float4*)(xrow + (i + 4) * 32);
        xa[i & 3][1] = *(const float4*)(xrow + (i + 4) * 32 + 4);
      }
      bf16x8 af;
      af[0] = (short)f2bf(a0.x); af[1] = (short)f2bf(a0.y);
      af[2] = (short)f2bf(a0.z); af[3] = (short)f2bf(a0.w);
      af[4] = (short)f2bf(a1.x); af[5] = (short)f2bf(a1.y);
      af[6] = (short)f2bf(a1.z); af[7] = (short)f2bf(a1.w);
      const bf16x8* bb = w1v + i * 320;
      acc0 = __builtin_amdgcn_mfma_f32_16x16x32_bf16(af, bb[0],   acc0, 0, 0, 0);
      acc1 = __builtin_amdgcn_mfma_f32_16x16x32_bf16(af, bb[64],  acc1, 0, 0, 0);
      acc2 = __builtin_amdgcn_mfma_f32_16x16x32_bf16(af, bb[128], acc2, 0, 0, 0);
      acc3 = __builtin_amdgcn_mfma_f32_16x16x32_bf16(af, bb[192], acc3, 0, 0, 0);
      acc4 = __builtin_amdgcn_mfma_f32_16x16x32_bf16(af, bb[256], acc4, 0, 0, 0);
    }
    int hr = tg * 16 + kgrp * 4;   // block-local token = tg*16 + (lane>>4)*4 + reg
    #pragma unroll
    for (int r = 0; r < 4; r++) {
      Hs[kh][hr + r][arow]      = acc0[r];
      Hs[kh][hr + r][16 + arow] = acc1[r];
      Hs[kh][hr + r][32 + arow] = acc2[r];
      Hs[kh][hr + r][48 + arow] = acc3[r];
      Hs[kh][hr + r][64 + arow] = acc4[r];
    }
  }
  __syncthreads();

  // middle: 128 threads, 4 per token
  if (tidx < 128) {
    int t = tidx >> 2;   // block-local token 0..31
    int c = tidx & 3;
    unsigned int* g2u = g2 + (size_t)(tok0 + t) * 48;
    float lg[8];
    float m = -1e30f;
    #pragma unroll
    for (int e = 0; e < 8; e++) {
      lg[e] = Hs[0][t][64 + e] + Hs[1][t][64 + e] + bg[e];
      m = fmaxf(m, lg[e]);
    }
    float den = 0.f;
    #pragma unroll
    for (int e = 0; e < 8; e++) { lg[e] = __expf(lg[e] - m); den += lg[e]; }
    float inv = 1.f / den;
    unsigned int hv[8];
    #pragma unroll
    for (int ee = 0; ee < 2; ee++) {
      int e = c * 2 + ee;
      float gate = lg[e] * inv;
      float h[8];
      #pragma unroll
      for (int r = 0; r < 8; r++)
        h[r] = Hs[0][t][e * 8 + r] + Hs[1][t][e * 8 + r] + bd[e * 8 + r];
      #pragma unroll
      for (int q = 0; q < 8; q += 2) {
        float h2a = bm[e * 8 + q], h2b = bm[e * 8 + q + 1];
        #pragma unroll
        for (int r = 0; r < 8; r++) {
          h2a += h[r] * Wm[e * 64 + r * 8 + q];
          h2b += h[r] * Wm[e * 64 + r * 8 + q + 1];
        }
        hv[ee * 4 + (q >> 1)] =
            (unsigned)f2bf(gate * h2a) | ((unsigned)f2bf(gate * h2b) << 16);
      }
    }
    *(uint4*)(g2u + 8 * c)     = make_uint4(hv[0], hv[1], hv[2], hv[3]);
    *(uint4*)(g2u + 8 * c + 4) = make_uint4(hv[4], hv[5], hv[6], hv[7]);
    g2u[32 + c] = (unsigned)f2bf(lg[c * 2] * inv) | ((unsigned)f2bf(lg[c * 2 + 1] * inv) << 16);
    g2u[36 + c * 3 + 0] = 0;
    g2u[36 + c * 3 + 1] = 0;
    g2u[36 + c * 3 + 2] = 0;
  }
}

// ---------------- k2: out = g2 @ W2, 32 tok/block, frag-triple reused x2 ----------------
// D = mfma(A=W2frag, B=g2frag): lane holds out[tok0+tg*16+(lane&15)][T*16+(lane>>4)*4 + 0..3].
__global__ __launch_bounds__(256) void k2_out(
    const unsigned short* __restrict__ g2bf, const unsigned short* __restrict__ w2f,
    float* __restrict__ out) {
  const int tidx = threadIdx.x;
  const int lane = tidx & 63;
  const int wave = tidx >> 6;       // T quarter (12 tiles)
  const int arow = lane & 15;       // token within group / out row
  const int kgrp = lane >> 4;
  const int tok0 = blockIdx.x * 32;

  const unsigned short* grow0 = g2bf + (size_t)(tok0 + arow) * 96 + kgrp * 8;
  const unsigned short* grow1 = grow0 + 16 * 96;
  bf16x8 a0_0 = *(const bf16x8*)(grow0);
  bf16x8 a0_1 = *(const bf16x8*)(grow0 + 32);
  bf16x8 a0_2 = *(const bf16x8*)(grow0 + 64);
  bf16x8 a1_0 = *(const bf16x8*)(grow1);
  bf16x8 a1_1 = *(const bf16x8*)(grow1 + 32);
  bf16x8 a1_2 = *(const bf16x8*)(grow1 + 64);

  const bf16x8* w2v = (const bf16x8*)w2f + (size_t)(wave * 12) * 192 + lane;
  float* orow0 = out + (size_t)(tok0 + arow) * 768 + wave * 192 + kgrp * 4;
  float* orow1 = orow0 + (size_t)16 * 768;

  bf16x8 pb[4][3];
  #pragma unroll
  for (int d = 0; d < 4; d++) {
    pb[d][0] = w2v[d * 192];
    pb[d][1] = w2v[d * 192 + 64];
    pb[d][2] = w2v[d * 192 + 128];
  }
  #pragma unroll
  for (int j = 0; j < 12; j++) {
    bf16x8 b0 = pb[j & 3][0], b1 = pb[j & 3][1], b2 = pb[j & 3][2];
    if (j + 4 < 12) {
      pb[j & 3][0] = w2v[(j + 4) * 192];
      pb[j & 3][1] = w2v[(j + 4) * 192 + 64];
      pb[j & 3][2] = w2v[(j + 4) * 192 + 128];
    }
    f32x4 c0 = {0,0,0,0}, c1 = {0,0,0,0};
    c0 = __builtin_amdgcn_mfma_f32_16x16x32_bf16(b0, a0_0, c0, 0, 0, 0);
    c1 = __builtin_amdgcn_mfma_f32_16x16x32_bf16(b0, a1_0, c1, 0, 0, 0);
    c0 = __builtin_amdgcn_mfma_f32_16x16x32_bf16(b1, a0_1, c0, 0, 0, 0);
    c1 = __builtin_amdgcn_mfma_f32_16x16x32_bf16(b1, a1_1, c1, 0, 0, 0);
    c0 = __builtin_amdgcn_mfma_f32_16x16x32_bf16(b2, a0_2, c0, 0, 0, 0);
    c1 = __builtin_amdgcn_mfma_f32_16x16x32_bf16(b2, a1_2, c1, 0, 0, 0);
    *(f32x4*)(orow0 + j * 16) = c0;
    *(f32x4*)(orow1 + j * 16) = c1;
  }
}

extern "C" void kernel_launch(void* const* d_in, const int* in_sizes, int n_in,
                              void* d_out, int out_size, void* d_ws, size_t ws_size,
                              hipStream_t stream) {
  const float* x  = (const float*)d_in[0];
  const float* Wd = (const float*)d_in[1];
  const float* bd = (const float*)d_in[2];
  const float* Wm = (const float*)d_in[3];
  const float* bm = (const float*)d_in[4];
  const float* Wu = (const float*)d_in[5];
  const float* bu = (const float*)d_in[6];
  const float* Wg = (const float*)d_in[7];
  const float* bg = (const float*)d_in[8];
  unsigned short* w1f = (unsigned short*)d_ws;                  // 61440 bf16
  unsigned short* w2f = w1f + 61440;                            // 73728 bf16
  unsigned int*   g2  = (unsigned int*)((char*)d_ws + 270336);  // 32768*48 u32 = 6 MB

  prep_weights<<<528, 256, 0, stream>>>(Wd, Wg, Wu, bu, w1f, w2f);
  k1_g2<<<1024, 256, 0, stream>>>(x, bd, Wm, bm, bg, w1f, g2);
  k2_out<<<1024, 256, 0, stream>>>((const unsigned short*)g2, w2f, (float*)d_out);
}

// Round 8
// 57.498 us; speedup vs baseline: 1.1273x; 1.0724x over previous
//
#include <hip/hip_runtime.h>
#include <stdint.h>

// B=8 S=4096 D=768 E=8 R=8; NTOK=32768
// GEMM1: H[NTOK,80] = x @ W1[768,80]   (W1 = [Wd(64) | Wg(8) | pad(8)])
// middle: softmax gate, h2 = (H+bd)@Wm+bm, g2 = [gate*h2 | gate | zeros]  (96 wide, bf16)
// GEMM2: out[NTOK,768] = g2 @ W2[96,768] (W2 rows = [Wu(64) | bu(8) | zeros(24)])
// Fused (R3 structure) + swapped-operand phase C (R6 store path): 32 tok/block, grid 1024.

typedef short bf16x8 __attribute__((ext_vector_type(8)));
typedef float f32x4 __attribute__((ext_vector_type(4)));

static __device__ __forceinline__ unsigned short f2bf(float f) {
  union { float f; uint32_t u; } v; v.f = f;
  return (unsigned short)((v.u + 0x7fffu + ((v.u >> 16) & 1u)) >> 16);
}

// w1f frags [K0(24)][f(5)][lane(64)][i(8)]: W1[K0*32+(lane>>4)*8+i][f*16+(lane&15)]
// w2f frags [T(48)][K0(3)][lane(64)][i(8)]: W2[K0*32+(lane>>4)*8+i][T*16+(lane&15)]
__global__ void prep_weights(const float* __restrict__ Wd, const float* __restrict__ Wg,
                             const float* __restrict__ Wu, const float* __restrict__ bu,
                             unsigned short* __restrict__ w1f, unsigned short* __restrict__ w2f) {
  int tid = blockIdx.x * 256 + threadIdx.x;
  const int N1 = 24 * 5 * 64 * 8;   // 61440
  if (tid < N1) {
    int i    = tid & 7;
    int lane = (tid >> 3) & 63;
    int fk   = tid >> 9;
    int f = fk % 5, K0 = fk / 5;
    int k = K0 * 32 + (lane >> 4) * 8 + i;
    int j = f * 16 + (lane & 15);
    float val = 0.f;
    if (j < 64)      val = Wd[(size_t)(j >> 3) * 6144 + (size_t)k * 8 + (j & 7)];
    else if (j < 72) val = Wg[(size_t)k * 8 + (j - 64)];
    w1f[tid] = f2bf(val);
  } else {
    int t2 = tid - N1;
    if (t2 >= 48 * 3 * 64 * 8) return;
    int i    = t2 & 7;
    int lane = (t2 >> 3) & 63;
    int tk   = t2 >> 9;
    int K0 = tk % 3, T = tk / 3;
    int k = K0 * 32 + (lane >> 4) * 8 + i;
    int n = T * 16 + (lane & 15);
    float val = 0.f;
    if (k < 64)      val = Wu[(size_t)(k >> 3) * 6144 + (size_t)(k & 7) * 768 + n];
    else if (k < 72) val = bu[(size_t)(k - 64) * 768 + n];
    w2f[t2] = f2bf(val);
  }
}

__global__ __launch_bounds__(256) void moba_fused(
    const float* __restrict__ x,
    const float* __restrict__ bd, const float* __restrict__ Wm,
    const float* __restrict__ bm, const float* __restrict__ bg,
    const unsigned short* __restrict__ w1f, const unsigned short* __restrict__ w2f,
    float* __restrict__ out) {
  __shared__ float Hs[2][32][84];       // 21504 B; store banks 2-way max (free)
  __shared__ unsigned int g2s[32][52];  //  6656 B; rows 16B-aligned (208 B stride)

  const int tidx = threadIdx.x;
  const int lane = tidx & 63;
  const int wave = tidx >> 6;
  const int tg   = wave >> 1;       // phase A: token group (16 tokens)
  const int kh   = wave & 1;        // phase A: K half
  const int arow = lane & 15;
  const int kgrp = lane >> 4;
  const int tok0 = blockIdx.x * 32;

  // ---------------- Phase A: H = x @ W1 (2-way K-split, 4-deep x prefetch) ----------------
  {
    const float* xrow = x + (size_t)(tok0 + tg * 16 + arow) * 768 + kh * 384 + kgrp * 8;
    f32x4 acc0 = {0,0,0,0}, acc1 = {0,0,0,0}, acc2 = {0,0,0,0}, acc3 = {0,0,0,0}, acc4 = {0,0,0,0};
    const bf16x8* w1v = (const bf16x8*)w1f + (size_t)(kh * 12) * 320 + lane;

    float4 xa[4][2];
    #pragma unroll
    for (int i = 0; i < 4; i++) {
      xa[i][0] = *(const float4*)(xrow + i * 32);
      xa[i][1] = *(const float4*)(xrow + i * 32 + 4);
    }
    #pragma unroll
    for (int i = 0; i < 12; i++) {
      float4 a0 = xa[i & 3][0];
      float4 a1 = xa[i & 3][1];
      if (i + 4 < 12) {
        xa[i & 3][0] = *(const float4*)(xrow + (i + 4) * 32);
        xa[i & 3][1] = *(const float4*)(xrow + (i + 4) * 32 + 4);
      }
      bf16x8 af;
      af[0] = (short)f2bf(a0.x); af[1] = (short)f2bf(a0.y);
      af[2] = (short)f2bf(a0.z); af[3] = (short)f2bf(a0.w);
      af[4] = (short)f2bf(a1.x); af[5] = (short)f2bf(a1.y);
      af[6] = (short)f2bf(a1.z); af[7] = (short)f2bf(a1.w);
      const bf16x8* bb = w1v + i * 320;
      acc0 = __builtin_amdgcn_mfma_f32_16x16x32_bf16(af, bb[0],   acc0, 0, 0, 0);
      acc1 = __builtin_amdgcn_mfma_f32_16x16x32_bf16(af, bb[64],  acc1, 0, 0, 0);
      acc2 = __builtin_amdgcn_mfma_f32_16x16x32_bf16(af, bb[128], acc2, 0, 0, 0);
      acc3 = __builtin_amdgcn_mfma_f32_16x16x32_bf16(af, bb[192], acc3, 0, 0, 0);
      acc4 = __builtin_amdgcn_mfma_f32_16x16x32_bf16(af, bb[256], acc4, 0, 0, 0);
    }
    int hr = tg * 16 + kgrp * 4;   // block-local token = tg*16 + (lane>>4)*4 + reg
    #pragma unroll
    for (int r = 0; r < 4; r++) {
      Hs[kh][hr + r][arow]      = acc0[r];
      Hs[kh][hr + r][16 + arow] = acc1[r];
      Hs[kh][hr + r][32 + arow] = acc2[r];
      Hs[kh][hr + r][48 + arow] = acc3[r];
      Hs[kh][hr + r][64 + arow] = acc4[r];
    }
  }
  __syncthreads();

  // ---------------- Phase B: middle (128 threads, 4 per token) ----------------
  if (tidx < 128) {
    int t = tidx >> 2;   // block-local token 0..31
    int c = tidx & 3;
    float lg[8];
    float m = -1e30f;
    #pragma unroll
    for (int e = 0; e < 8; e++) {
      lg[e] = Hs[0][t][64 + e] + Hs[1][t][64 + e] + bg[e];
      m = fmaxf(m, lg[e]);
    }
    float den = 0.f;
    #pragma unroll
    for (int e = 0; e < 8; e++) { lg[e] = __expf(lg[e] - m); den += lg[e]; }
    float inv = 1.f / den;
    unsigned int hv[8];
    #pragma unroll
    for (int ee = 0; ee < 2; ee++) {
      int e = c * 2 + ee;
      float gate = lg[e] * inv;
      float h[8];
      #pragma unroll
      for (int r = 0; r < 8; r++)
        h[r] = Hs[0][t][e * 8 + r] + Hs[1][t][e * 8 + r] + bd[e * 8 + r];
      #pragma unroll
      for (int q = 0; q < 8; q += 2) {
        float h2a = bm[e * 8 + q], h2b = bm[e * 8 + q + 1];
        #pragma unroll
        for (int r = 0; r < 8; r++) {
          h2a += h[r] * Wm[e * 64 + r * 8 + q];
          h2b += h[r] * Wm[e * 64 + r * 8 + q + 1];
        }
        hv[ee * 4 + (q >> 1)] =
            (unsigned)f2bf(gate * h2a) | ((unsigned)f2bf(gate * h2b) << 16);
      }
    }
    *(uint4*)&g2s[t][8 * c]     = make_uint4(hv[0], hv[1], hv[2], hv[3]);
    *(uint4*)&g2s[t][8 * c + 4] = make_uint4(hv[4], hv[5], hv[6], hv[7]);
    g2s[t][32 + c] = (unsigned)f2bf(lg[c * 2] * inv) | ((unsigned)f2bf(lg[c * 2 + 1] * inv) << 16);
    g2s[t][36 + c * 3 + 0] = 0;
    g2s[t][36 + c * 3 + 1] = 0;
    g2s[t][36 + c * 3 + 2] = 0;
  }
  __syncthreads();

  // ---------------- Phase C: out = g2 @ W2, swapped operands, frag-triple reused x2 ----------
  // D = mfma(A=W2frag, B=g2frag): lane holds out[tok0+g*16+(lane&15)][T*16+(lane>>4)*4+0..3].
  bf16x8 a0_0 = *(const bf16x8*)&g2s[arow][kgrp * 4];
  bf16x8 a0_1 = *(const bf16x8*)&g2s[arow][16 + kgrp * 4];
  bf16x8 a0_2 = *(const bf16x8*)&g2s[arow][32 + kgrp * 4];
  bf16x8 a1_0 = *(const bf16x8*)&g2s[16 + arow][kgrp * 4];
  bf16x8 a1_1 = *(const bf16x8*)&g2s[16 + arow][16 + kgrp * 4];
  bf16x8 a1_2 = *(const bf16x8*)&g2s[16 + arow][32 + kgrp * 4];

  const bf16x8* w2v = (const bf16x8*)w2f + (size_t)(wave * 12) * 192 + lane;
  float* orow0 = out + (size_t)(tok0 + arow) * 768 + wave * 192 + kgrp * 4;
  float* orow1 = orow0 + (size_t)16 * 768;

  bf16x8 pb[2][3];
  #pragma unroll
  for (int d = 0; d < 2; d++) {
    pb[d][0] = w2v[d * 192];
    pb[d][1] = w2v[d * 192 + 64];
    pb[d][2] = w2v[d * 192 + 128];
  }
  #pragma unroll
  for (int j = 0; j < 12; j++) {
    bf16x8 b0 = pb[j & 1][0], b1 = pb[j & 1][1], b2 = pb[j & 1][2];
    if (j + 2 < 12) {
      pb[j & 1][0] = w2v[(j + 2) * 192];
      pb[j & 1][1] = w2v[(j + 2) * 192 + 64];
      pb[j & 1][2] = w2v[(j + 2) * 192 + 128];
    }
    f32x4 c0 = {0,0,0,0}, c1 = {0,0,0,0};
    c0 = __builtin_amdgcn_mfma_f32_16x16x32_bf16(b0, a0_0, c0, 0, 0, 0);
    c1 = __builtin_amdgcn_mfma_f32_16x16x32_bf16(b0, a1_0, c1, 0, 0, 0);
    c0 = __builtin_amdgcn_mfma_f32_16x16x32_bf16(b1, a0_1, c0, 0, 0, 0);
    c1 = __builtin_amdgcn_mfma_f32_16x16x32_bf16(b1, a1_1, c1, 0, 0, 0);
    c0 = __builtin_amdgcn_mfma_f32_16x16x32_bf16(b2, a0_2, c0, 0, 0, 0);
    c1 = __builtin_amdgcn_mfma_f32_16x16x32_bf16(b2, a1_2, c1, 0, 0, 0);
    *(f32x4*)(orow0 + j * 16) = c0;
    *(f32x4*)(orow1 + j * 16) = c1;
  }
}

extern "C" void kernel_launch(void* const* d_in, const int* in_sizes, int n_in,
                              void* d_out, int out_size, void* d_ws, size_t ws_size,
                              hipStream_t stream) {
  const float* x  = (const float*)d_in[0];
  const float* Wd = (const float*)d_in[1];
  const float* bd = (const float*)d_in[2];
  const float* Wm = (const float*)d_in[3];
  const float* bm = (const float*)d_in[4];
  const float* Wu = (const float*)d_in[5];
  const float* bu = (const float*)d_in[6];
  const float* Wg = (const float*)d_in[7];
  const float* bg = (const float*)d_in[8];
  unsigned short* w1f = (unsigned short*)d_ws;          // 61440 bf16
  unsigned short* w2f = w1f + 61440;                    // 73728 bf16

  prep_weights<<<528, 256, 0, stream>>>(Wd, Wg, Wu, bu, w1f, w2f);
  moba_fused<<<1024, 256, 0, stream>>>(x, bd, Wm, bm, bg, w1f, w2f, (float*)d_out);
}